// Round 9
// baseline (128.328 us; speedup 1.0000x reference)
//
#include <hip/hip_runtime.h>
#include <hip/hip_bf16.h>

// Problem constants (fixed): n=4, b=8192, a=32, c_in=32, d_out=32,
// n_basis=36 (4 radii x 9 SH), ck=1152.
// inputs: [0] input (4,32,8192) f32, [1] coords (4,8192,3) f32,
//         [2] relative_mask (4,8192,32) f32, [3] W (32,32,36) f32,
//         [4] neighbors (4,8192,32) i32
// output: (4,32,8192) f32
//
// R9 = R8 + Wfrag register hoist: each wave's 9 phase-2 W-fragments (36
// VGPRs) are loaded at kernel entry, overlapping phase-1 gathers/geometry,
// so phase 2 after the barrier is pure LDS+MFMA (no exposed global latency).

typedef _Float16 f16x8 __attribute__((ext_vector_type(8)));
typedef _Float16 f16x4 __attribute__((ext_vector_type(4)));
typedef __fp16   h16x2 __attribute__((ext_vector_type(2)));
typedef float    f32x4 __attribute__((ext_vector_type(4)));
typedef unsigned int u32;

__device__ __forceinline__ u32 pk16(float a, float b) {
    union { h16x2 v; u32 u; } cv;
    cv.v = __builtin_amdgcn_cvt_pkrtz(a, b);
    return cv.u;
}
__device__ __forceinline__ unsigned short f16bits(float v) {
    const _Float16 hv = (_Float16)v;
    return __builtin_bit_cast(unsigned short, hv);
}

#define BAS_STRIDE 44   // u16 per phys row (88B, b64-aligned, reads <=2-way)

// geometry: SH l=0..2 and the h-half radial pair (mask folded in)
__device__ __forceinline__ void geom(float dx, float dy, float dz, float msk, int h_,
                                     float Y[9], float& rbA, float& rbB) {
    const float r   = sqrtf(dx * dx + dy * dy + dz * dz);
    const float inv = 1.0f / (r + 1e-8f);
    const float x = dx * inv, y = dy * inv, z = dz * inv;
    Y[0] = 0.28209479f;
    Y[1] = 0.48860251f * x;
    Y[2] = 0.48860251f * y;
    Y[3] = 0.48860251f * z;
    Y[4] = 1.09254843f * x * y;
    Y[5] = 1.09254843f * y * z;
    Y[6] = 0.31539157f * (3.0f * z * z - 1.0f);
    Y[7] = 1.09254843f * x * z;
    Y[8] = 0.54627421f * (x * x - y * y);
    const float t0 = (r - 0.5f) * 2.0f;
    const float t1 = (r - 1.0f) * 2.0f;
    const float t2 = (r - 1.5f) * 2.0f;
    const float t3 = (r - 2.0f) * 2.0f;
    const float rb0 = __expf(-t0 * t0) * msk;
    const float rb1 = __expf(-t1 * t1) * msk;
    const float rb2 = __expf(-t2 * t2) * msk;
    const float rb3 = __expf(-t3 * t3) * msk;
    rbA = h_ ? rb2 : rb0;
    rbB = h_ ? rb3 : rb1;
}

// ---------------- prep: LDS-tiled transpose (f32 -> f16) + W -> MFMA-A fragments ----------
// Wfrag[t], t = ((kt*2+dt)*64 + l)*8 + j  holds  W[d][c*36 + k'] as f16, where
// d = dt*16 + (l&15), c = (l>>4)*8+j, k' = kt.
__global__ __launch_bounds__(256) void prep_kernel(
    const float* __restrict__ inp, const float* __restrict__ W,
    unsigned short* __restrict__ inp_t16, unsigned short* __restrict__ Wfrag)
{
    if (blockIdx.x < 1024) {
        __shared__ float T[32][33];
        const int n  = blockIdx.x >> 8;
        const int b0 = (blockIdx.x & 255) << 5;
        const int bx = threadIdx.x & 31;
        const int cy = threadIdx.x >> 5;   // 0..7
        #pragma unroll
        for (int r = 0; r < 4; ++r) {
            const int cc = cy + r * 8;
            T[bx][cc] = inp[((n << 5) + cc) * 8192 + b0 + bx];
        }
        __syncthreads();
        #pragma unroll
        for (int r = 0; r < 4; ++r) {
            const int by = cy + r * 8;
            inp_t16[((n << 13) + b0 + by) * 32 + bx] = f16bits(T[by][bx]);
        }
    } else {
        const int t = (blockIdx.x - 1024) * 256 + threadIdx.x;   // 0..36863
        if (t < 36 * 2 * 64 * 8) {
            const int j  = t & 7;
            const int l  = (t >> 3) & 63;
            const int dt = (t >> 9) & 1;
            const int kt = t >> 10;                  // k' = 0..35
            const int d  = dt * 16 + (l & 15);
            const int c  = ((l >> 4) << 3) + j;
            Wfrag[t] = f16bits(W[d * 1152 + c * 36 + kt]);
        }
    }
}

// ---------------- main fused kernel: 512 threads, 16 points/block, 2 passes/wave ----------
__global__ __launch_bounds__(512, 4) void se3_main(
    const unsigned short* __restrict__ inp_t16, const float* __restrict__ coords,
    const float* __restrict__ rmask, const int* __restrict__ neigh,
    const unsigned short* __restrict__ Wfrag, float* __restrict__ out)
{
    // Mb[k'=0..35][p=0..15][c=0..31] f16; p-row 72B, plane 1160B (580 us, 8B pad).
    __shared__ __align__(16) unsigned short Mb_s[36 * 580];          // 41,760 B
    // basis^T per wave: phys = 2t + h interleave, 37 rows x 44 us.
    __shared__ __align__(16) unsigned short bas[8][37 * BAS_STRIDE]; // 26,048 B
    __shared__ unsigned short idxs[16][32];                          //  1,024 B
    __shared__ __align__(16) float Cp[8 * 64 * 4];                   //  8,192 B
    // total 77,024 B -> 2 blocks/CU = 16 waves/CU

    const int tid  = threadIdx.x;
    const int lane = tid & 63;
    const int w    = tid >> 6;      // wave 0..7
    const int l15  = lane & 15;
    const int q    = lane >> 4;     // 0..3
    const int a_   = lane & 31;
    const int h_   = lane >> 5;

    // XCD-aware swizzle: XCD pair {2n,2n+1} serves batch n
    const int blk = blockIdx.x;
    const int n_  = (blk & 7) >> 1;
    const int pos = ((blk >> 3) << 1) | (blk & 1);
    const int b0  = pos << 4;
    const int gp0 = (n_ << 13) | b0;
    const int nbase_pt = n_ << 13;
    const unsigned short* __restrict__ inp_n = inp_t16 + ((size_t)n_ << 18);

    unsigned short* basw = &bas[w][0];

    // ---- R9: hoist this wave's 9 phase-2 W-fragments into VGPRs (overlaps phase 1) ----
    const int dt  = w >> 2;       // 0,1
    const int seg = w & 3;        // 9 kt-steps each
    const int kt0 = seg * 9;
    f16x8 wf[9];
    #pragma unroll
    for (int i = 0; i < 9; ++i) {
        const int kt = kt0 + i;
        wf[i] = *(const f16x8*)&Wfrag[((size_t)((kt * 2 + dt) * 64 + lane)) << 3];
    }

    // basis^T read rows per nt: phys(k') = k'<18 ? 2k' : (k'<36 ? 2k'-35 : 36)
    const int ph0 = 2 * l15;
    const int ph1 = (l15 < 2) ? (32 + 2 * l15) : (2 * l15 - 3);
    const int ph2 = (l15 < 4) ? (29 + 2 * l15) : 36;
    const int offB0 = ph0 * BAS_STRIDE + (q << 3);
    const int offB1 = ph1 * BAS_STRIDE + (q << 3);
    const int offB2 = ph2 * BAS_STRIDE + (q << 3);

    const int pA = w << 1, pB = pA | 1;
    const int gpA = gp0 + pA, gpB = gp0 + pB;

    // ================= hoisted global loads (both passes) =================
    const int   idxA = neigh[(gpA << 5) | a_];
    const int   idxB = neigh[(gpB << 5) | a_];
    const float mskA = rmask[(gpA << 5) | a_];
    const float mskB = rmask[(gpB << 5) | a_];
    const float cxA = coords[gpA * 3 + 0], cyA = coords[gpA * 3 + 1], czA = coords[gpA * 3 + 2];
    const float cxB = coords[gpB * 3 + 0], cyB = coords[gpB * 3 + 1], czB = coords[gpB * 3 + 2];
    if (lane < 32) {
        idxs[pA][a_] = (unsigned short)idxA;
        idxs[pB][a_] = (unsigned short)idxB;
    }
    const int nbA = (nbase_pt + idxA) * 3;
    const int nbB = (nbase_pt + idxB) * 3;
    const float dxA = coords[nbA + 0] - cxA, dyA = coords[nbA + 1] - cyA, dzA = coords[nbA + 2] - czA;
    const float dxB = coords[nbB + 0] - cxB, dyB = coords[nbB + 1] - cyB, dzB = coords[nbB + 2] - czB;

    // feat gathers for both passes (u16 loads; ridx via same-wave LDS, in-order DS)
    u32 fA0[8], fA1[8], fB0[8], fB1[8];
    #pragma unroll
    for (int j = 0; j < 8; ++j) {
        const int ri = idxs[pA][(q << 3) + j];
        const unsigned short* rp = inp_n + (((unsigned)ri) << 5) + l15;
        fA0[j] = rp[0];    // c = l15      (mt=0)
        fA1[j] = rp[16];   // c = l15 + 16 (mt=1)
    }
    #pragma unroll
    for (int j = 0; j < 8; ++j) {
        const int ri = idxs[pB][(q << 3) + j];
        const unsigned short* rp = inp_n + (((unsigned)ri) << 5) + l15;
        fB0[j] = rp[0];
        fB1[j] = rp[16];
    }

    // ================= geometry (VALU, overlaps the gathers) =================
    float YA[9], YB[9], rbA_A, rbB_A, rbA_B, rbB_B;
    geom(dxA, dyA, dzA, mskA, h_, YA, rbA_A, rbB_A);
    geom(dxB, dyB, dzB, mskB, h_, YB, rbA_B, rbB_B);

    // bas-A writes: k = 18h + t, phys row = 2t + h
    #pragma unroll
    for (int t = 0; t < 18; ++t) {
        const float v = (t < 9) ? rbA_A * YA[t] : rbB_A * YA[t - 9];
        basw[(2 * t + h_) * BAS_STRIDE + a_] = f16bits(v);
    }

    // Bf-A reads (b64; <=2-way banks); before bas-B writes (same-wave DS order)
    f16x4 blo, bhi;
    blo = *(const f16x4*)&basw[offB0]; bhi = *(const f16x4*)&basw[offB0 + 4];
    const f16x8 BfA0 = __builtin_shufflevector(blo, bhi, 0, 1, 2, 3, 4, 5, 6, 7);
    blo = *(const f16x4*)&basw[offB1]; bhi = *(const f16x4*)&basw[offB1 + 4];
    const f16x8 BfA1 = __builtin_shufflevector(blo, bhi, 0, 1, 2, 3, 4, 5, 6, 7);
    blo = *(const f16x4*)&basw[offB2]; bhi = *(const f16x4*)&basw[offB2 + 4];
    const f16x8 BfA2 = __builtin_shufflevector(blo, bhi, 0, 1, 2, 3, 4, 5, 6, 7);

    // assemble A-fragments from u16 halves (feat already f16 in memory)
    union { f16x8 v; u32 u[4]; } afA0, afA1, afB0, afB1;
    #pragma unroll
    for (int j4 = 0; j4 < 4; ++j4) {
        afA0.u[j4] = fA0[2 * j4] | (fA0[2 * j4 + 1] << 16);
        afA1.u[j4] = fA1[2 * j4] | (fA1[2 * j4 + 1] << 16);
    }
    const f32x4 z4 = {0.0f, 0.0f, 0.0f, 0.0f};
    f32x4 DA00 = __builtin_amdgcn_mfma_f32_16x16x32_f16(afA0.v, BfA0, z4, 0, 0, 0);
    f32x4 DA01 = __builtin_amdgcn_mfma_f32_16x16x32_f16(afA0.v, BfA1, z4, 0, 0, 0);
    f32x4 DA02 = __builtin_amdgcn_mfma_f32_16x16x32_f16(afA0.v, BfA2, z4, 0, 0, 0);
    f32x4 DA10 = __builtin_amdgcn_mfma_f32_16x16x32_f16(afA1.v, BfA0, z4, 0, 0, 0);
    f32x4 DA11 = __builtin_amdgcn_mfma_f32_16x16x32_f16(afA1.v, BfA1, z4, 0, 0, 0);
    f32x4 DA12 = __builtin_amdgcn_mfma_f32_16x16x32_f16(afA1.v, BfA2, z4, 0, 0, 0);

    // bas-B writes (after Bf-A reads in program order)
    #pragma unroll
    for (int t = 0; t < 18; ++t) {
        const float v = (t < 9) ? rbA_B * YB[t] : rbB_B * YB[t - 9];
        basw[(2 * t + h_) * BAS_STRIDE + a_] = f16bits(v);
    }
    blo = *(const f16x4*)&basw[offB0]; bhi = *(const f16x4*)&basw[offB0 + 4];
    const f16x8 BfB0 = __builtin_shufflevector(blo, bhi, 0, 1, 2, 3, 4, 5, 6, 7);
    blo = *(const f16x4*)&basw[offB1]; bhi = *(const f16x4*)&basw[offB1 + 4];
    const f16x8 BfB1 = __builtin_shufflevector(blo, bhi, 0, 1, 2, 3, 4, 5, 6, 7);
    blo = *(const f16x4*)&basw[offB2]; bhi = *(const f16x4*)&basw[offB2 + 4];
    const f16x8 BfB2 = __builtin_shufflevector(blo, bhi, 0, 1, 2, 3, 4, 5, 6, 7);

    #pragma unroll
    for (int j4 = 0; j4 < 4; ++j4) {
        afB0.u[j4] = fB0[2 * j4] | (fB0[2 * j4 + 1] << 16);
        afB1.u[j4] = fB1[2 * j4] | (fB1[2 * j4 + 1] << 16);
    }
    f32x4 DB00 = __builtin_amdgcn_mfma_f32_16x16x32_f16(afB0.v, BfB0, z4, 0, 0, 0);
    f32x4 DB01 = __builtin_amdgcn_mfma_f32_16x16x32_f16(afB0.v, BfB1, z4, 0, 0, 0);
    f32x4 DB02 = __builtin_amdgcn_mfma_f32_16x16x32_f16(afB0.v, BfB2, z4, 0, 0, 0);
    f32x4 DB10 = __builtin_amdgcn_mfma_f32_16x16x32_f16(afB1.v, BfB0, z4, 0, 0, 0);
    f32x4 DB11 = __builtin_amdgcn_mfma_f32_16x16x32_f16(afB1.v, BfB1, z4, 0, 0, 0);
    f32x4 DB12 = __builtin_amdgcn_mfma_f32_16x16x32_f16(afB1.v, BfB2, z4, 0, 0, 0);

    // ---- D -> Mb[k'][p][c]: reg pairs = consecutive c -> single b32 writes ----
    {
        const int rowpA = pA * 36 + (q << 2);
        const int a0 = l15 * 580 + rowpA;          // nt=0
        const int a1 = (16 + l15) * 580 + rowpA;   // nt=1
        *(u32*)&Mb_s[a0]      = pk16(DA00[0], DA00[1]);
        *(u32*)&Mb_s[a0 + 2]  = pk16(DA00[2], DA00[3]);
        *(u32*)&Mb_s[a0 + 16] = pk16(DA10[0], DA10[1]);
        *(u32*)&Mb_s[a0 + 18] = pk16(DA10[2], DA10[3]);
        *(u32*)&Mb_s[a1]      = pk16(DA01[0], DA01[1]);
        *(u32*)&Mb_s[a1 + 2]  = pk16(DA01[2], DA01[3]);
        *(u32*)&Mb_s[a1 + 16] = pk16(DA11[0], DA11[1]);
        *(u32*)&Mb_s[a1 + 18] = pk16(DA11[2], DA11[3]);
        const int rowpB = pB * 36 + (q << 2);
        const int c0 = l15 * 580 + rowpB;
        const int c1 = (16 + l15) * 580 + rowpB;
        *(u32*)&Mb_s[c0]      = pk16(DB00[0], DB00[1]);
        *(u32*)&Mb_s[c0 + 2]  = pk16(DB00[2], DB00[3]);
        *(u32*)&Mb_s[c0 + 16] = pk16(DB10[0], DB10[1]);
        *(u32*)&Mb_s[c0 + 18] = pk16(DB10[2], DB10[3]);
        *(u32*)&Mb_s[c1]      = pk16(DB01[0], DB01[1]);
        *(u32*)&Mb_s[c1 + 2]  = pk16(DB01[2], DB01[3]);
        *(u32*)&Mb_s[c1 + 16] = pk16(DB11[0], DB11[1]);
        *(u32*)&Mb_s[c1 + 18] = pk16(DB11[2], DB11[3]);
        if (l15 < 4) {   // nt=2: k' = 32..35
            const int a2 = (32 + l15) * 580 + rowpA;
            *(u32*)&Mb_s[a2]      = pk16(DA02[0], DA02[1]);
            *(u32*)&Mb_s[a2 + 2]  = pk16(DA02[2], DA02[3]);
            *(u32*)&Mb_s[a2 + 16] = pk16(DA12[0], DA12[1]);
            *(u32*)&Mb_s[a2 + 18] = pk16(DA12[2], DA12[3]);
            const int c2 = (32 + l15) * 580 + rowpB;
            *(u32*)&Mb_s[c2]      = pk16(DB02[0], DB02[1]);
            *(u32*)&Mb_s[c2 + 2]  = pk16(DB02[2], DB02[3]);
            *(u32*)&Mb_s[c2 + 16] = pk16(DB12[0], DB12[1]);
            *(u32*)&Mb_s[c2 + 18] = pk16(DB12[2], DB12[3]);
        }
    }
    __syncthreads();

    // ============ Phase 2: pure LDS + MFMA (W already in registers) ============
    {
        f32x4 acc2 = {0.0f, 0.0f, 0.0f, 0.0f};
        #pragma unroll 3
        for (int i = 0; i < 9; ++i) {
            const int kt = kt0 + i;
            const int mbase = kt * 580 + l15 * 36 + (q << 3);
            const f16x4 mlo = *(const f16x4*)&Mb_s[mbase];
            const f16x4 mhi = *(const f16x4*)&Mb_s[mbase + 4];
            const f16x8 bf  = __builtin_shufflevector(mlo, mhi, 0, 1, 2, 3, 4, 5, 6, 7);
            acc2 = __builtin_amdgcn_mfma_f32_16x16x32_f16(wf[i], bf, acc2, 0, 0, 0);
        }
        *(f32x4*)&Cp[(w * 64 + lane) * 4] = acc2;   // dedicated buffer
    }
    __syncthreads();

    if (w < 2) {
        const int dt2 = w;
        f32x4 s = *(const f32x4*)&Cp[((dt2 * 4 + 0) * 64 + lane) * 4];
        #pragma unroll
        for (int rphase = 1; rphase < 4; ++rphase) {
            const f32x4 t = *(const f32x4*)&Cp[((dt2 * 4 + rphase) * 64 + lane) * 4];
            s[0] += t[0]; s[1] += t[1]; s[2] += t[2]; s[3] += t[3];
        }
        const int drow = dt2 * 16 + (lane >> 4) * 4;   // D row = (lane>>4)*4 + reg
        const int col  = b0 + (lane & 15);
        #pragma unroll
        for (int rr = 0; rr < 4; ++rr) {
            out[(((n_ << 5) + drow + rr) << 13) + col] = s[rr];
        }
    }
}

extern "C" void kernel_launch(void* const* d_in, const int* in_sizes, int n_in,
                              void* d_out, int out_size, void* d_ws, size_t ws_size,
                              hipStream_t stream)
{
    const float* inp    = (const float*)d_in[0];
    const float* coords = (const float*)d_in[1];
    const float* rmask  = (const float*)d_in[2];
    const float* W      = (const float*)d_in[3];
    const int*   neigh  = (const int*)d_in[4];
    float*       outp   = (float*)d_out;

    unsigned short* inp_t16 = (unsigned short*)d_ws;                        // 2 MB f16
    unsigned short* Wfrag   = (unsigned short*)((char*)d_ws + (2u << 20));  // 73.7 KB

    prep_kernel<<<1168, 256, 0, stream>>>(inp, W, inp_t16, Wfrag);
    se3_main<<<2048, 512, 0, stream>>>(inp_t16, coords, rmask, neigh, Wfrag, outp);
}

// Round 10
// 90.316 us; speedup vs baseline: 1.4209x; 1.4209x over previous
//
#include <hip/hip_runtime.h>
#include <hip/hip_bf16.h>

// Problem constants (fixed): n=4, b=8192, a=32, c_in=32, d_out=32,
// n_basis=36 (4 radii x 9 SH), ck=1152.
// inputs: [0] input (4,32,8192) f32, [1] coords (4,8192,3) f32,
//         [2] relative_mask (4,8192,32) f32, [3] W (32,32,36) f32,
//         [4] neighbors (4,8192,32) i32
// output: (4,32,8192) f32
//
// R10 = R9 with the spill fixed: phase-2 loop FULLY unrolled so wf[9] gets
// static indices and stays in VGPRs (R9's "#pragma unroll 3" made wf[i]
// dynamically indexed -> scratch array -> 230 MB spill traffic, VGPR=52,
// +35 us). Structure otherwise identical to R8/R9: 16 pts/block, 512 thr,
// 2 passes/wave, 2 blocks/CU, bas stride 44, f16 inp_t.

typedef _Float16 f16x8 __attribute__((ext_vector_type(8)));
typedef _Float16 f16x4 __attribute__((ext_vector_type(4)));
typedef __fp16   h16x2 __attribute__((ext_vector_type(2)));
typedef float    f32x4 __attribute__((ext_vector_type(4)));
typedef unsigned int u32;

__device__ __forceinline__ u32 pk16(float a, float b) {
    union { h16x2 v; u32 u; } cv;
    cv.v = __builtin_amdgcn_cvt_pkrtz(a, b);
    return cv.u;
}
__device__ __forceinline__ unsigned short f16bits(float v) {
    const _Float16 hv = (_Float16)v;
    return __builtin_bit_cast(unsigned short, hv);
}

#define BAS_STRIDE 44   // u16 per phys row (88B, b64-aligned, reads <=2-way)

// geometry: SH l=0..2 and the h-half radial pair (mask folded in)
__device__ __forceinline__ void geom(float dx, float dy, float dz, float msk, int h_,
                                     float Y[9], float& rbA, float& rbB) {
    const float r   = sqrtf(dx * dx + dy * dy + dz * dz);
    const float inv = 1.0f / (r + 1e-8f);
    const float x = dx * inv, y = dy * inv, z = dz * inv;
    Y[0] = 0.28209479f;
    Y[1] = 0.48860251f * x;
    Y[2] = 0.48860251f * y;
    Y[3] = 0.48860251f * z;
    Y[4] = 1.09254843f * x * y;
    Y[5] = 1.09254843f * y * z;
    Y[6] = 0.31539157f * (3.0f * z * z - 1.0f);
    Y[7] = 1.09254843f * x * z;
    Y[8] = 0.54627421f * (x * x - y * y);
    const float t0 = (r - 0.5f) * 2.0f;
    const float t1 = (r - 1.0f) * 2.0f;
    const float t2 = (r - 1.5f) * 2.0f;
    const float t3 = (r - 2.0f) * 2.0f;
    const float rb0 = __expf(-t0 * t0) * msk;
    const float rb1 = __expf(-t1 * t1) * msk;
    const float rb2 = __expf(-t2 * t2) * msk;
    const float rb3 = __expf(-t3 * t3) * msk;
    rbA = h_ ? rb2 : rb0;
    rbB = h_ ? rb3 : rb1;
}

// ---------------- prep: LDS-tiled transpose (f32 -> f16) + W -> MFMA-A fragments ----------
// Wfrag[t], t = ((kt*2+dt)*64 + l)*8 + j  holds  W[d][c*36 + k'] as f16, where
// d = dt*16 + (l&15), c = (l>>4)*8+j, k' = kt.
__global__ __launch_bounds__(256) void prep_kernel(
    const float* __restrict__ inp, const float* __restrict__ W,
    unsigned short* __restrict__ inp_t16, unsigned short* __restrict__ Wfrag)
{
    if (blockIdx.x < 1024) {
        __shared__ float T[32][33];
        const int n  = blockIdx.x >> 8;
        const int b0 = (blockIdx.x & 255) << 5;
        const int bx = threadIdx.x & 31;
        const int cy = threadIdx.x >> 5;   // 0..7
        #pragma unroll
        for (int r = 0; r < 4; ++r) {
            const int cc = cy + r * 8;
            T[bx][cc] = inp[((n << 5) + cc) * 8192 + b0 + bx];
        }
        __syncthreads();
        #pragma unroll
        for (int r = 0; r < 4; ++r) {
            const int by = cy + r * 8;
            inp_t16[((n << 13) + b0 + by) * 32 + bx] = f16bits(T[by][bx]);
        }
    } else {
        const int t = (blockIdx.x - 1024) * 256 + threadIdx.x;   // 0..36863
        if (t < 36 * 2 * 64 * 8) {
            const int j  = t & 7;
            const int l  = (t >> 3) & 63;
            const int dt = (t >> 9) & 1;
            const int kt = t >> 10;                  // k' = 0..35
            const int d  = dt * 16 + (l & 15);
            const int c  = ((l >> 4) << 3) + j;
            Wfrag[t] = f16bits(W[d * 1152 + c * 36 + kt]);
        }
    }
}

// ---------------- main fused kernel: 512 threads, 16 points/block, 2 passes/wave ----------
__global__ __launch_bounds__(512, 4) void se3_main(
    const unsigned short* __restrict__ inp_t16, const float* __restrict__ coords,
    const float* __restrict__ rmask, const int* __restrict__ neigh,
    const unsigned short* __restrict__ Wfrag, float* __restrict__ out)
{
    // Mb[k'=0..35][p=0..15][c=0..31] f16; p-row 72B, plane 1160B (580 us, 8B pad).
    __shared__ __align__(16) unsigned short Mb_s[36 * 580];          // 41,760 B
    // basis^T per wave: phys = 2t + h interleave, 37 rows x 44 us.
    __shared__ __align__(16) unsigned short bas[8][37 * BAS_STRIDE]; // 26,048 B
    __shared__ unsigned short idxs[16][32];                          //  1,024 B
    __shared__ __align__(16) float Cp[8 * 64 * 4];                   //  8,192 B
    // total 77,024 B -> 2 blocks/CU = 16 waves/CU

    const int tid  = threadIdx.x;
    const int lane = tid & 63;
    const int w    = tid >> 6;      // wave 0..7
    const int l15  = lane & 15;
    const int q    = lane >> 4;     // 0..3
    const int a_   = lane & 31;
    const int h_   = lane >> 5;

    // XCD-aware swizzle: XCD pair {2n,2n+1} serves batch n
    const int blk = blockIdx.x;
    const int n_  = (blk & 7) >> 1;
    const int pos = ((blk >> 3) << 1) | (blk & 1);
    const int b0  = pos << 4;
    const int gp0 = (n_ << 13) | b0;
    const int nbase_pt = n_ << 13;
    const unsigned short* __restrict__ inp_n = inp_t16 + ((size_t)n_ << 18);

    unsigned short* basw = &bas[w][0];

    // ---- hoist this wave's 9 phase-2 W-fragments into VGPRs (overlaps phase 1) ----
    const int dt  = w >> 2;       // 0,1
    const int seg = w & 3;        // 9 kt-steps each
    const int kt0 = seg * 9;
    f16x8 wf0, wf1, wf2, wf3, wf4, wf5, wf6, wf7, wf8;
    {
        const unsigned short* wb = &Wfrag[((size_t)((kt0 * 2 + dt) * 64 + lane)) << 3];
        // consecutive kt step in Wfrag: +2*64*8 = +1024 u16
        wf0 = *(const f16x8*)(wb + 0 * 1024);
        wf1 = *(const f16x8*)(wb + 1 * 1024);
        wf2 = *(const f16x8*)(wb + 2 * 1024);
        wf3 = *(const f16x8*)(wb + 3 * 1024);
        wf4 = *(const f16x8*)(wb + 4 * 1024);
        wf5 = *(const f16x8*)(wb + 5 * 1024);
        wf6 = *(const f16x8*)(wb + 6 * 1024);
        wf7 = *(const f16x8*)(wb + 7 * 1024);
        wf8 = *(const f16x8*)(wb + 8 * 1024);
    }

    // basis^T read rows per nt: phys(k') = k'<18 ? 2k' : (k'<36 ? 2k'-35 : 36)
    const int ph0 = 2 * l15;
    const int ph1 = (l15 < 2) ? (32 + 2 * l15) : (2 * l15 - 3);
    const int ph2 = (l15 < 4) ? (29 + 2 * l15) : 36;
    const int offB0 = ph0 * BAS_STRIDE + (q << 3);
    const int offB1 = ph1 * BAS_STRIDE + (q << 3);
    const int offB2 = ph2 * BAS_STRIDE + (q << 3);

    const int pA = w << 1, pB = pA | 1;
    const int gpA = gp0 + pA, gpB = gp0 + pB;

    // ================= hoisted global loads (both passes) =================
    const int   idxA = neigh[(gpA << 5) | a_];
    const int   idxB = neigh[(gpB << 5) | a_];
    const float mskA = rmask[(gpA << 5) | a_];
    const float mskB = rmask[(gpB << 5) | a_];
    const float cxA = coords[gpA * 3 + 0], cyA = coords[gpA * 3 + 1], czA = coords[gpA * 3 + 2];
    const float cxB = coords[gpB * 3 + 0], cyB = coords[gpB * 3 + 1], czB = coords[gpB * 3 + 2];
    if (lane < 32) {
        idxs[pA][a_] = (unsigned short)idxA;
        idxs[pB][a_] = (unsigned short)idxB;
    }
    const int nbA = (nbase_pt + idxA) * 3;
    const int nbB = (nbase_pt + idxB) * 3;
    const float dxA = coords[nbA + 0] - cxA, dyA = coords[nbA + 1] - cyA, dzA = coords[nbA + 2] - czA;
    const float dxB = coords[nbB + 0] - cxB, dyB = coords[nbB + 1] - cyB, dzB = coords[nbB + 2] - czB;

    // feat gathers for both passes (u16 loads; ridx via same-wave LDS, in-order DS)
    u32 fA0[8], fA1[8], fB0[8], fB1[8];
    #pragma unroll
    for (int j = 0; j < 8; ++j) {
        const int ri = idxs[pA][(q << 3) + j];
        const unsigned short* rp = inp_n + (((unsigned)ri) << 5) + l15;
        fA0[j] = rp[0];    // c = l15      (mt=0)
        fA1[j] = rp[16];   // c = l15 + 16 (mt=1)
    }
    #pragma unroll
    for (int j = 0; j < 8; ++j) {
        const int ri = idxs[pB][(q << 3) + j];
        const unsigned short* rp = inp_n + (((unsigned)ri) << 5) + l15;
        fB0[j] = rp[0];
        fB1[j] = rp[16];
    }

    // ================= geometry (VALU, overlaps the gathers) =================
    float YA[9], YB[9], rbA_A, rbB_A, rbA_B, rbB_B;
    geom(dxA, dyA, dzA, mskA, h_, YA, rbA_A, rbB_A);
    geom(dxB, dyB, dzB, mskB, h_, YB, rbA_B, rbB_B);

    // bas-A writes: k = 18h + t, phys row = 2t + h
    #pragma unroll
    for (int t = 0; t < 18; ++t) {
        const float v = (t < 9) ? rbA_A * YA[t] : rbB_A * YA[t - 9];
        basw[(2 * t + h_) * BAS_STRIDE + a_] = f16bits(v);
    }

    // Bf-A reads (b64; <=2-way banks); before bas-B writes (same-wave DS order)
    f16x4 blo, bhi;
    blo = *(const f16x4*)&basw[offB0]; bhi = *(const f16x4*)&basw[offB0 + 4];
    const f16x8 BfA0 = __builtin_shufflevector(blo, bhi, 0, 1, 2, 3, 4, 5, 6, 7);
    blo = *(const f16x4*)&basw[offB1]; bhi = *(const f16x4*)&basw[offB1 + 4];
    const f16x8 BfA1 = __builtin_shufflevector(blo, bhi, 0, 1, 2, 3, 4, 5, 6, 7);
    blo = *(const f16x4*)&basw[offB2]; bhi = *(const f16x4*)&basw[offB2 + 4];
    const f16x8 BfA2 = __builtin_shufflevector(blo, bhi, 0, 1, 2, 3, 4, 5, 6, 7);

    // assemble A-fragments from u16 halves (feat already f16 in memory)
    union { f16x8 v; u32 u[4]; } afA0, afA1, afB0, afB1;
    #pragma unroll
    for (int j4 = 0; j4 < 4; ++j4) {
        afA0.u[j4] = fA0[2 * j4] | (fA0[2 * j4 + 1] << 16);
        afA1.u[j4] = fA1[2 * j4] | (fA1[2 * j4 + 1] << 16);
    }
    const f32x4 z4 = {0.0f, 0.0f, 0.0f, 0.0f};
    f32x4 DA00 = __builtin_amdgcn_mfma_f32_16x16x32_f16(afA0.v, BfA0, z4, 0, 0, 0);
    f32x4 DA01 = __builtin_amdgcn_mfma_f32_16x16x32_f16(afA0.v, BfA1, z4, 0, 0, 0);
    f32x4 DA02 = __builtin_amdgcn_mfma_f32_16x16x32_f16(afA0.v, BfA2, z4, 0, 0, 0);
    f32x4 DA10 = __builtin_amdgcn_mfma_f32_16x16x32_f16(afA1.v, BfA0, z4, 0, 0, 0);
    f32x4 DA11 = __builtin_amdgcn_mfma_f32_16x16x32_f16(afA1.v, BfA1, z4, 0, 0, 0);
    f32x4 DA12 = __builtin_amdgcn_mfma_f32_16x16x32_f16(afA1.v, BfA2, z4, 0, 0, 0);

    // bas-B writes (after Bf-A reads in program order)
    #pragma unroll
    for (int t = 0; t < 18; ++t) {
        const float v = (t < 9) ? rbA_B * YB[t] : rbB_B * YB[t - 9];
        basw[(2 * t + h_) * BAS_STRIDE + a_] = f16bits(v);
    }
    blo = *(const f16x4*)&basw[offB0]; bhi = *(const f16x4*)&basw[offB0 + 4];
    const f16x8 BfB0 = __builtin_shufflevector(blo, bhi, 0, 1, 2, 3, 4, 5, 6, 7);
    blo = *(const f16x4*)&basw[offB1]; bhi = *(const f16x4*)&basw[offB1 + 4];
    const f16x8 BfB1 = __builtin_shufflevector(blo, bhi, 0, 1, 2, 3, 4, 5, 6, 7);
    blo = *(const f16x4*)&basw[offB2]; bhi = *(const f16x4*)&basw[offB2 + 4];
    const f16x8 BfB2 = __builtin_shufflevector(blo, bhi, 0, 1, 2, 3, 4, 5, 6, 7);

    #pragma unroll
    for (int j4 = 0; j4 < 4; ++j4) {
        afB0.u[j4] = fB0[2 * j4] | (fB0[2 * j4 + 1] << 16);
        afB1.u[j4] = fB1[2 * j4] | (fB1[2 * j4 + 1] << 16);
    }
    f32x4 DB00 = __builtin_amdgcn_mfma_f32_16x16x32_f16(afB0.v, BfB0, z4, 0, 0, 0);
    f32x4 DB01 = __builtin_amdgcn_mfma_f32_16x16x32_f16(afB0.v, BfB1, z4, 0, 0, 0);
    f32x4 DB02 = __builtin_amdgcn_mfma_f32_16x16x32_f16(afB0.v, BfB2, z4, 0, 0, 0);
    f32x4 DB10 = __builtin_amdgcn_mfma_f32_16x16x32_f16(afB1.v, BfB0, z4, 0, 0, 0);
    f32x4 DB11 = __builtin_amdgcn_mfma_f32_16x16x32_f16(afB1.v, BfB1, z4, 0, 0, 0);
    f32x4 DB12 = __builtin_amdgcn_mfma_f32_16x16x32_f16(afB1.v, BfB2, z4, 0, 0, 0);

    // ---- D -> Mb[k'][p][c]: reg pairs = consecutive c -> single b32 writes ----
    {
        const int rowpA = pA * 36 + (q << 2);
        const int a0 = l15 * 580 + rowpA;          // nt=0
        const int a1 = (16 + l15) * 580 + rowpA;   // nt=1
        *(u32*)&Mb_s[a0]      = pk16(DA00[0], DA00[1]);
        *(u32*)&Mb_s[a0 + 2]  = pk16(DA00[2], DA00[3]);
        *(u32*)&Mb_s[a0 + 16] = pk16(DA10[0], DA10[1]);
        *(u32*)&Mb_s[a0 + 18] = pk16(DA10[2], DA10[3]);
        *(u32*)&Mb_s[a1]      = pk16(DA01[0], DA01[1]);
        *(u32*)&Mb_s[a1 + 2]  = pk16(DA01[2], DA01[3]);
        *(u32*)&Mb_s[a1 + 16] = pk16(DA11[0], DA11[1]);
        *(u32*)&Mb_s[a1 + 18] = pk16(DA11[2], DA11[3]);
        const int rowpB = pB * 36 + (q << 2);
        const int c0 = l15 * 580 + rowpB;
        const int c1 = (16 + l15) * 580 + rowpB;
        *(u32*)&Mb_s[c0]      = pk16(DB00[0], DB00[1]);
        *(u32*)&Mb_s[c0 + 2]  = pk16(DB00[2], DB00[3]);
        *(u32*)&Mb_s[c0 + 16] = pk16(DB10[0], DB10[1]);
        *(u32*)&Mb_s[c0 + 18] = pk16(DB10[2], DB10[3]);
        *(u32*)&Mb_s[c1]      = pk16(DB01[0], DB01[1]);
        *(u32*)&Mb_s[c1 + 2]  = pk16(DB01[2], DB01[3]);
        *(u32*)&Mb_s[c1 + 16] = pk16(DB11[0], DB11[1]);
        *(u32*)&Mb_s[c1 + 18] = pk16(DB11[2], DB11[3]);
        if (l15 < 4) {   // nt=2: k' = 32..35
            const int a2 = (32 + l15) * 580 + rowpA;
            *(u32*)&Mb_s[a2]      = pk16(DA02[0], DA02[1]);
            *(u32*)&Mb_s[a2 + 2]  = pk16(DA02[2], DA02[3]);
            *(u32*)&Mb_s[a2 + 16] = pk16(DA12[0], DA12[1]);
            *(u32*)&Mb_s[a2 + 18] = pk16(DA12[2], DA12[3]);
            const int c2 = (32 + l15) * 580 + rowpB;
            *(u32*)&Mb_s[c2]      = pk16(DB02[0], DB02[1]);
            *(u32*)&Mb_s[c2 + 2]  = pk16(DB02[2], DB02[3]);
            *(u32*)&Mb_s[c2 + 16] = pk16(DB12[0], DB12[1]);
            *(u32*)&Mb_s[c2 + 18] = pk16(DB12[2], DB12[3]);
        }
    }
    __syncthreads();

    // ============ Phase 2: pure LDS + MFMA, fully unrolled (wf stays in VGPRs) ============
    {
        f32x4 acc2 = {0.0f, 0.0f, 0.0f, 0.0f};
        #define P2_STEP(I, WF)                                                       \
        {                                                                            \
            const int mbase = (kt0 + I) * 580 + l15 * 36 + (q << 3);                 \
            const f16x4 mlo = *(const f16x4*)&Mb_s[mbase];                           \
            const f16x4 mhi = *(const f16x4*)&Mb_s[mbase + 4];                       \
            const f16x8 bf  = __builtin_shufflevector(mlo, mhi, 0,1,2,3,4,5,6,7);    \
            acc2 = __builtin_amdgcn_mfma_f32_16x16x32_f16(WF, bf, acc2, 0, 0, 0);    \
        }
        P2_STEP(0, wf0) P2_STEP(1, wf1) P2_STEP(2, wf2)
        P2_STEP(3, wf3) P2_STEP(4, wf4) P2_STEP(5, wf5)
        P2_STEP(6, wf6) P2_STEP(7, wf7) P2_STEP(8, wf8)
        #undef P2_STEP
        *(f32x4*)&Cp[(w * 64 + lane) * 4] = acc2;   // dedicated buffer
    }
    __syncthreads();

    if (w < 2) {
        const int dt2 = w;
        f32x4 s = *(const f32x4*)&Cp[((dt2 * 4 + 0) * 64 + lane) * 4];
        #pragma unroll
        for (int rphase = 1; rphase < 4; ++rphase) {
            const f32x4 t = *(const f32x4*)&Cp[((dt2 * 4 + rphase) * 64 + lane) * 4];
            s[0] += t[0]; s[1] += t[1]; s[2] += t[2]; s[3] += t[3];
        }
        const int drow = dt2 * 16 + (lane >> 4) * 4;   // D row = (lane>>4)*4 + reg
        const int col  = b0 + (lane & 15);
        #pragma unroll
        for (int rr = 0; rr < 4; ++rr) {
            out[(((n_ << 5) + drow + rr) << 13) + col] = s[rr];
        }
    }
}

extern "C" void kernel_launch(void* const* d_in, const int* in_sizes, int n_in,
                              void* d_out, int out_size, void* d_ws, size_t ws_size,
                              hipStream_t stream)
{
    const float* inp    = (const float*)d_in[0];
    const float* coords = (const float*)d_in[1];
    const float* rmask  = (const float*)d_in[2];
    const float* W      = (const float*)d_in[3];
    const int*   neigh  = (const int*)d_in[4];
    float*       outp   = (float*)d_out;

    unsigned short* inp_t16 = (unsigned short*)d_ws;                        // 2 MB f16
    unsigned short* Wfrag   = (unsigned short*)((char*)d_ws + (2u << 20));  // 73.7 KB

    prep_kernel<<<1168, 256, 0, stream>>>(inp, W, inp_t16, Wfrag);
    se3_main<<<2048, 512, 0, stream>>>(inp_t16, coords, rmask, neigh, Wfrag, outp);
}